// Round 7
// baseline (255.473 us; speedup 1.0000x reference)
//
#include <hip/hip_runtime.h>
#include <stdint.h>

#define H_ 192
#define W_ 192
#define C_ 64
#define EPS_F 1e-8f
#define TILE 16
#define NTX (W_/TILE)
#define NTY (H_/TILE)
#define NTILES (NTX*NTY)
#define CHUNK 256
#define NSLICE 8
#define NBUCKET 256
#define MAXCHUNK 64

typedef unsigned long long ull;

// Output layout (floats), concatenated in reference return order:
// feats (H*W*C) | p2f (H*W) | zbuf (H*W) | bary (H*W*3) | dists (H*W)
#define OFF_FEATS 0
#define OFF_P2F   (H_*W_*C_)
#define OFF_ZBUF  (OFF_P2F + H_*W_)
#define OFF_BARY  (OFF_ZBUF + H_*W_)
#define OFF_DIST  (OFF_BARY + H_*W_*3)

// IEEE-exact ops (block FMA contraction; match numpy float32 op-for-op)
__device__ __forceinline__ float xm(float a, float b){ return __fmul_rn(a,b); }
__device__ __forceinline__ float xa(float a, float b){ return __fadd_rn(a,b); }
__device__ __forceinline__ float xsb(float a, float b){ return __fsub_rn(a,b); }
__device__ __forceinline__ float xd(float a, float b){ return __fdiv_rn(a,b); }

__device__ __forceinline__ float pixcoord(int i, float dim){
    float t = xa(xm(2.0f, (float)i), 1.0f);
    return xsb(1.0f, xd(t, dim));
}

// monotone float<->uint encode (order-preserving). Identity for atomicMax is 0.
// min(x) is tracked as max(fenc(-x)): ALL four bbox trackers init to 0x00000000.
__device__ __forceinline__ unsigned fenc(float f){
    unsigned b = __float_as_uint(f);
    return (b & 0x80000000u) ? ~b : (b | 0x80000000u);
}
__device__ __forceinline__ float fdec(unsigned e){
    unsigned b = (e & 0x80000000u) ? (e & 0x7FFFFFFFu) : ~e;
    return __uint_as_float(b);
}

// depth bucket: fixed mapping. zlo(b) below must lower-bound every zmin in b.
__device__ __forceinline__ int zbucket(float zmn){
    int b = (int)((zmn - 2.0f) * 64.0f);
    return b < 0 ? 0 : (b > 254 ? 254 : b);
}
__device__ __forceinline__ float zlo_bucket(int b){
    if (b >= 255) return INFINITY;      // dead bucket (or beyond end)
    if (b == 0)   return 0.0f;          // bucket 0 catches all small z
    return 2.0f + (float)b * 0.015625f; // faces in b have zmin >= 2 + b/64
}

// Vertex transform — computed ONCE (k_pre); consumers read the stored bits.
__device__ __forceinline__ float3 tv(const float* __restrict__ pos,
        const float* __restrict__ K, const float* __restrict__ RT, int i){
    float p0 = pos[3*i+0], p1 = pos[3*i+1], p2 = pos[3*i+2];
    const float sgn[3] = {-1.f, -1.f, 1.f};
    float vv[3];
    #pragma unroll
    for (int j=0;j<3;j++){
        float rp0 = xm(RT[j*4+0], sgn[j]);
        float rp1 = xm(RT[j*4+1], sgn[j]);
        float rp2 = xm(RT[j*4+2], sgn[j]);
        float s = xa(xa(xm(p0,rp0), xm(p1,rp1)), xm(p2,rp2));
        vv[j] = xa(s, xm(RT[j*4+3], sgn[j]));
    }
    float z = vv[2];
    float fx = xd(K[0], 96.0f);
    float fy = xd(K[4], 96.0f);
    float p0x = -xd(xsb(K[2], 96.0f), 96.0f);
    float p0y = -xd(xsb(K[5], 96.0f), 96.0f);
    float xn = xa(xd(xm(fx, vv[0]), z), p0x);
    float yn = xa(xd(xm(fy, vv[1]), z), p0y);
    return make_float3(xn, yn, z);
}

// Launch 2 of 4 (256 blocks x 64 thr): transform verts once, write unsorted
// record rec0[f], LDS histogram -> non-returning global adds, wave-reduced
// bbox (all-atomicMax), and grid-stride clear of keys (replaces big memset).
// rec0 (3 float4): q0 x0,y0,x1,y1 | q1 x2,y2,z0,z1 | q2 z2,ia,fid,zmin
__global__ __launch_bounds__(64) void k_pre(const float* __restrict__ pos,
        const float* __restrict__ K, const float* __restrict__ RT,
        const int* __restrict__ faces, float* __restrict__ rec0,
        unsigned* __restrict__ hist, unsigned* __restrict__ gbb,
        ull* __restrict__ keys, int Fn){
    __shared__ unsigned lh[NBUCKET];
    int t = threadIdx.x, B = blockIdx.x;
    int gthreads = gridDim.x*64;
    for (int i = B*64 + t; i < H_*W_; i += gthreads) keys[i] = 0xFFFFFFFFFFFFFFFFULL;
    #pragma unroll
    for (int i=t; i<NBUCKET; i+=64) lh[i] = 0u;
    __syncthreads();
    int f = B*64 + t;
    float bxmn=INFINITY, bxmx=-INFINITY, bymn=INFINITY, bymx=-INFINITY;
    if (f < Fn){
        int i0 = faces[3*f+0], i1 = faces[3*f+1], i2 = faces[3*f+2];
        float3 v0 = tv(pos,K,RT,i0), v1 = tv(pos,K,RT,i1), v2 = tv(pos,K,RT,i2);
        float area = xsb(xm(xsb(v1.x,v0.x), xsb(v2.y,v0.y)), xm(xsb(v1.y,v0.y), xsb(v2.x,v0.x)));
        bool ok = (area > EPS_F) && (v0.z > 0.f) && (v1.z > 0.f) && (v2.z > 0.f);
        float ia = ok ? xd(1.0f, area) : 0.0f;
        float zmn = INFINITY;
        int b = 255;
        if (ok){
            zmn = fminf(v0.z, fminf(v1.z, v2.z));
            b = zbucket(zmn);
            bxmn = fminf(v0.x, fminf(v1.x, v2.x)) - 1e-4f;
            bxmx = fmaxf(v0.x, fmaxf(v1.x, v2.x)) + 1e-4f;
            bymn = fminf(v0.y, fminf(v1.y, v2.y)) - 1e-4f;
            bymx = fmaxf(v0.y, fmaxf(v1.y, v2.y)) + 1e-4f;
        }
        atomicAdd(&lh[b], 1u);
        float4* q = (float4*)(rec0 + (size_t)f*12);
        q[0] = make_float4(v0.x, v0.y, v1.x, v1.y);
        q[1] = make_float4(v2.x, v2.y, v0.z, v1.z);
        q[2] = make_float4(v2.z, ia, __int_as_float(f), zmn);
    }
    // single-wave bbox reduce -> 4 non-returning atomics per block
    #pragma unroll
    for (int s2=1; s2<64; s2<<=1){
        bxmn = fminf(bxmn, __shfl_xor(bxmn, s2, 64));
        bxmx = fmaxf(bxmx, __shfl_xor(bxmx, s2, 64));
        bymn = fminf(bymn, __shfl_xor(bymn, s2, 64));
        bymx = fmaxf(bymx, __shfl_xor(bymx, s2, 64));
    }
    if (t == 0 && bxmx > -INFINITY){   // skip all-dead blocks
        atomicMax(&gbb[0], fenc(-bxmn));   // min x  as max of fenc(-x)
        atomicMax(&gbb[1], fenc( bxmx));
        atomicMax(&gbb[2], fenc(-bymn));
        atomicMax(&gbb[3], fenc( bymx));
    }
    __syncthreads();
    #pragma unroll
    for (int i=t; i<NBUCKET; i+=64){
        unsigned cc = lh[i];
        if (cc) atomicAdd(&hist[i], cc);   // non-returning, <=256 contenders
    }
}

// Launch 3 of 4 (64 blocks x 256): read summed hist, LDS scan, LDS-rank +
// one returning global atomic per (block,bucket), permute rec0 -> depth-sorted
// rec. Block 0 derives analytic chunk z-bounds suffz[] from the scan.
// rec: q0 x0,y0,x1,y1 | q1 x2,y2,z0,z1 | q2 z2,ia,fid,zmin | q3 A,B,C,0 | q4 xmn,xmx,ymn,ymx
__global__ __launch_bounds__(256) void k_scatter(const float* __restrict__ rec0,
        const unsigned* __restrict__ hist, unsigned* __restrict__ histcur,
        float* __restrict__ rec, float* __restrict__ suffz, int Fn){
    __shared__ unsigned gst[NBUCKET], ssc[NBUCKET], lcnt[NBUCKET], lbase[NBUCKET];
    int t = threadIdx.x, B = blockIdx.x;
    unsigned hv = hist[t];
    ssc[t] = hv;
    lcnt[t] = 0u;
    __syncthreads();
    for (int d=1; d<NBUCKET; d<<=1){
        unsigned u = (t >= d) ? ssc[t-d] : 0u;
        __syncthreads();
        ssc[t] += u;
        __syncthreads();
    }
    gst[t] = ssc[t] - hv;   // exclusive global bucket start
    __syncthreads();
    // Block 0: suffz[c] = zlo(bucket containing sorted position c*CHUNK).
    // Buckets ascend in z, so this is simultaneously the suffix-min bound.
    if (B == 0 && t < MAXCHUNK){
        unsigned pos = (unsigned)t * CHUNK;
        int bb = 0;
        #pragma unroll
        for (int s = 128; s > 0; s >>= 1){
            int nb = bb + s;
            if (nb <= NBUCKET && ssc[nb-1] <= pos) bb = nb;
        }
        suffz[t] = zlo_bucket(bb);   // bb==256 (pos>=Fn) -> INF via >=255
    }
    int f = B*256 + t;
    bool valid = (f < Fn);
    float4 q0, q1, q2;
    int b = 255; unsigned rank = 0; bool ok = false; float zmn = INFINITY;
    if (valid){
        const float4* q = (const float4*)(rec0 + (size_t)f*12);
        q0 = q[0]; q1 = q[1]; q2 = q[2];
        ok = (q2.y > 0.f);            // ia > 0 <=> face live
        zmn = q2.w;
        b = ok ? zbucket(zmn) : 255;
        rank = atomicAdd(&lcnt[b], 1u);     // LDS intra-block rank
    }
    __syncthreads();
    unsigned add = lcnt[t];
    if (add) lbase[t] = atomicAdd(&histcur[t], add);  // one per (block,bucket)
    __syncthreads();
    if (valid){
        float x0=q0.x, y0=q0.y, x1=q0.z, y1=q0.w;
        float x2=q1.x, y2=q1.y, z0=q1.z, z1=q1.w;
        float z2=q2.x, ia=q2.y;
        float xmn, xmx, ymn, ymx, Ap=0.f, Bp=0.f, Cp=0.f;
        if (ok){
            xmn = fminf(x0, fminf(x1, x2)) - 1e-4f;
            xmx = fmaxf(x0, fmaxf(x1, x2)) + 1e-4f;
            ymn = fminf(y0, fminf(y1, y2)) - 1e-4f;
            ymx = fmaxf(y0, fmaxf(y1, y2)) + 1e-4f;
            // 1/zp = C + A*px + B*py  (filter-only; margins absorb FP error)
            float iz0 = 1.f/z0, iz1 = 1.f/z1, iz2 = 1.f/z2;
            Ap = ia * ((y1-y2)*iz0 + (y2-y0)*iz1 + (y0-y1)*iz2);
            Bp = ia * ((x2-x1)*iz0 + (x0-x2)*iz1 + (x1-x0)*iz2);
            Cp = ia * ((x1*y2-x2*y1)*iz0 + (x2*y0-x0*y2)*iz1 + (x0*y1-x1*y0)*iz2);
        } else {
            xmn = INFINITY; xmx = -INFINITY; ymn = INFINITY; ymx = -INFINITY;
        }
        unsigned p = gst[b] + lbase[b] + rank;   // unique depth-sorted slot
        float4* qo = (float4*)(rec + (size_t)p*20);
        qo[0] = q0; qo[1] = q1; qo[2] = q2;
        qo[3] = make_float4(Ap, Bp, Cp, 0.f);
        qo[4] = make_float4(xmn, xmx, ymn, ymx);
    }
}

// Launch 4 of 4: tiled raster + FUSED shade. Each tile's last-finishing slice
// block (per-tile atomic counter) shades the tile, so shading of early tiles
// overlaps the raster tail. All skips provably conservative vs the FINAL key.
__global__ __launch_bounds__(256) void k_raster(const float* __restrict__ rec,
        const float* __restrict__ suffz, const unsigned* __restrict__ gbb,
        ull* __restrict__ keys, unsigned* __restrict__ tilecnt,
        const float* __restrict__ rec0, const float* __restrict__ feats,
        const int* __restrict__ faces, float* __restrict__ out, int Fn){
    __shared__ float lds[CHUNK*12];
    __shared__ float zl[CHUNK];       // per-tile z lower bound of survivors
    __shared__ int   slist[CHUNK];
    __shared__ int   wcnt[4];
    __shared__ float suff[MAXCHUNK];  // analytic chunk z-bounds (already suffix-min)
    __shared__ int   lastflag;
    int tid = threadIdx.x;
    int nchunk = (Fn + CHUNK - 1) / CHUNK;
    if (tid < MAXCHUNK) suff[tid] = suffz[tid];
    int ix = blockIdx.x*TILE + (tid & 15);
    int iy = blockIdx.y*TILE + (tid >> 4);
    int pix = iy*W_ + ix;
    float px = pixcoord(ix, (float)W_);
    float py = pixcoord(iy, (float)H_);
    float tx_hi = pixcoord(blockIdx.x*TILE,          (float)W_);
    float tx_lo = pixcoord(blockIdx.x*TILE + TILE-1, (float)W_);
    float ty_hi = pixcoord(blockIdx.y*TILE,          (float)H_);
    float ty_lo = pixcoord(blockIdx.y*TILE + TILE-1, (float)H_);
    float gx0 = -fdec(gbb[0]), gx1 = fdec(gbb[1]);   // NaN (no live faces) -> alive=false
    float gy0 = -fdec(gbb[2]), gy1 = fdec(gbb[3]);
    bool alive = (px >= gx0) && (px <= gx1) && (py >= gy0) && (py <= gy1);
    int lane = tid & 63, wv = tid >> 6;

    float zcut = INFINITY;
    ull localkey = 0xFFFFFFFFFFFFFFFFULL;
    ull published = 0xFFFFFFFFFFFFFFFFULL;
    __syncthreads();             // suff[] ready

    for (int c = (int)blockIdx.z; c < nchunk; c += NSLICE){
        // share depth convergence across slice blocks (stale reads conservative)
        ull g = __hip_atomic_load(&keys[pix], __ATOMIC_RELAXED, __HIP_MEMORY_SCOPE_AGENT);
        float zg = __uint_as_float((unsigned)(g >> 32));   // NaN if empty -> fminf ignores
        zcut = fminf(zcut, zg);
        float sc = (c < MAXCHUNK) ? suff[c] : 0.0f;
        int done = (!alive || !(xm(sc, 0.999f) < zcut)) ? 1 : 0;
        if (__syncthreads_and(done)) break;    // barrier also protects lds reuse

        int fi = c*CHUNK + tid;
        float4 q0 = make_float4(0,0,0,0), q1 = q0, q2 = q0;
        bool keep = false;
        float zb = 0.f;
        if (fi < Fn){
            const float4* gq = (const float4*)(rec + (size_t)fi*20);
            q0 = gq[0]; q1 = gq[1]; q2 = gq[2];
            float4 q3 = gq[3], q4 = gq[4];
            keep = (q4.x <= tx_hi) && (q4.y >= tx_lo) && (q4.z <= ty_hi) && (q4.w >= ty_lo);
            if (keep){
                // tile z lower bound from the linear 1/z plane (corner max + margin)
                float ax = (q3.x > 0.f) ? tx_hi : tx_lo;
                float by = (q3.y > 0.f) ? ty_hi : ty_lo;
                float Nmax = q3.z + q3.x*ax + q3.y*by;
                float M = fabsf(q3.x*ax) + fabsf(q3.y*by) + fabsf(q3.z);
                float Nub = Nmax + 1e-5f*M + 1e-30f;
                if (Nub <= 0.f) keep = false;          // no coverage possible in tile
                else zb = fmaxf(1.f/Nub, q2.w);        // max(plane bound, face zmin)
            }
        }
        float4* l = (float4*)(lds + tid*12);
        l[0] = q0; l[1] = q1; l[2] = q2;
        ull m = __ballot(keep);
        if (lane == 0) wcnt[wv] = __popcll(m);
        __syncthreads();
        int basecnt = 0;
        #pragma unroll
        for (int w2 = 0; w2 < 4; ++w2) if (w2 < wv) basecnt += wcnt[w2];
        if (keep){
            int p = basecnt + __popcll(m & ((1ULL << lane) - 1ULL));
            slist[p] = tid;
            zl[p] = zb;
        }
        int nsurv = wcnt[0] + wcnt[1] + wcnt[2] + wcnt[3];
        __syncthreads();

        for (int k = 0; k < nsurv; k++){
            float zbl = zl[k];
            if (!(xm(zbl, 0.999f) < zcut)) continue;   // conservative tile-z pre-check
            int j = slist[k];
            const float* r = lds + j*12;
            float x0=r[0], y0=r[1], x1=r[2], y1=r[3], x2=r[4], y2=r[5];
            float dx0=xsb(x0,px), dx1=xsb(x1,px), dx2=xsb(x2,px);
            float dy0=xsb(y0,py), dy1=xsb(y1,py), dy2=xsb(y2,py);
            float e0 = xsb(xm(dx1,dy2), xm(dy1,dx2));
            float e1 = xsb(xm(dx2,dy0), xm(dy2,dx0));
            float e2 = xsb(xm(dx0,dy1), xm(dy0,dx1));
            if (e0 >= 0.f && e1 >= 0.f && e2 >= 0.f){
                float z0=r[6], z1=r[7], z2=r[8], ia=r[9];
                float w0 = xm(e0, ia), w1 = xm(e1, ia), w2 = xm(e2, ia);
                float l0 = xm(xm(w0,z1),z2);
                float l1 = xm(xm(z0,w1),z2);
                float l2 = xm(xm(z0,z1),w2);
                float s  = xa(xa(l0,l1),l2);
                // cheap-z filter (1 divide); skip only when provably worse than zcut.
                float za = (l0*z0 + l1*z1 + l2*z2) / s;
                if (za*0.99999f >= zcut) continue;
                float dn = (s == 0.f) ? 1.0f : s;
                float b0 = fmaxf(xd(l0,dn), 0.f);
                float b1 = fmaxf(xd(l1,dn), 0.f);
                float b2 = fmaxf(xd(l2,dn), 0.f);
                float bs = fmaxf(xa(xa(b0,b1),b2), EPS_F);
                b0 = xd(b0,bs); b1 = xd(b1,bs); b2 = xd(b2,bs);
                float zp = xa(xa(xm(b0,z0),xm(b1,z1)),xm(b2,z2));
                // packed (z, orig_fid) key: exact argmin-first tie semantics
                ull ck = (((ull)__float_as_uint(zp)) << 32) | (unsigned)__float_as_int(r[10]);
                if (ck < localkey) localkey = ck;
                zcut = fminf(zcut, zp);
            }
        }
        if (localkey < published){     // publish so other slice blocks can break
            atomicMin(&keys[pix], localkey);
            published = localkey;
        }
    }
    if (localkey < published) atomicMin(&keys[pix], localkey);

    // -------- fused shade: last slice block of this tile shades it --------
    __threadfence();                       // release our key writes
    if (tid == 0){
        unsigned o = atomicAdd(&tilecnt[blockIdx.y*NTX + blockIdx.x], 1u);
        lastflag = (o == NSLICE-1) ? 1 : 0;
    }
    __syncthreads();
    if (!lastflag) return;
    __threadfence();                       // acquire: all slices' keys visible

    int grp = tid >> 6, c = tid & 63;
    float* p2f  = out + OFF_P2F;
    float* zbuf = out + OFF_ZBUF;
    float* bary = out + OFF_BARY;
    float* dist = out + OFF_DIST;
    for (int pp = 0; pp < 64; ++pp){
        int pixloc = pp*4 + grp;               // 0..255 within tile
        int ix2 = blockIdx.x*TILE + (pixloc & 15);
        int iy2 = blockIdx.y*TILE + (pixloc >> 4);
        int pix2 = iy2*W_ + ix2;
        ull key = __hip_atomic_load(&keys[pix2], __ATOMIC_RELAXED, __HIP_MEMORY_SCOPE_AGENT);
        if (key == 0xFFFFFFFFFFFFFFFFULL){
            out[OFF_FEATS + pix2*C_ + c] = 0.0f;
            if (c == 0){ p2f[pix2] = -1.0f; zbuf[pix2] = -1.0f; dist[pix2] = -1.0f; }
            if (c < 3) bary[3*pix2+c] = -1.0f;
            continue;
        }
        int f = (int)(key & 0xFFFFFFFFu);
        float z = __uint_as_float((unsigned)(key >> 32));
        float px2 = pixcoord(ix2, (float)W_);
        float py2 = pixcoord(iy2, (float)H_);
        const float4* q = (const float4*)(rec0 + (size_t)f*12);
        float4 q0 = q[0], q1 = q[1], q2 = q[2];
        float x0=q0.x, y0=q0.y, x1=q0.z, y1=q0.w;
        float x2=q1.x, y2=q1.y, z0=q1.z, z1=q1.w;
        float z2=q2.x, ia=q2.y;
        float w0 = xm(xsb(xm(xsb(x1,px2),xsb(y2,py2)), xm(xsb(y1,py2),xsb(x2,px2))), ia);
        float w1 = xm(xsb(xm(xsb(x2,px2),xsb(y0,py2)), xm(xsb(y2,py2),xsb(x0,px2))), ia);
        float w2 = xm(xsb(xm(xsb(x0,px2),xsb(y1,py2)), xm(xsb(y0,py2),xsb(x1,px2))), ia);
        float l0 = xm(xm(w0,z1),z2);
        float l1 = xm(xm(z0,w1),z2);
        float l2 = xm(xm(z0,z1),w2);
        float s  = xa(xa(l0,l1),l2);
        float dn = (s == 0.f) ? 1.0f : s;
        float b0 = fmaxf(xd(l0,dn), 0.f);
        float b1 = fmaxf(xd(l1,dn), 0.f);
        float b2 = fmaxf(xd(l2,dn), 0.f);
        float bs = fmaxf(xa(xa(b0,b1),b2), EPS_F);
        b0 = xd(b0,bs); b1 = xd(b1,bs); b2 = xd(b2,bs);
        int i0 = faces[3*f+0], i1 = faces[3*f+1], i2 = faces[3*f+2];
        float res = xa(xa(xm(b0, feats[i0*C_ + c]), xm(b1, feats[i1*C_ + c])),
                       xm(b2, feats[i2*C_ + c]));
        out[OFF_FEATS + pix2*C_ + c] = res;
        if (c == 0){ p2f[pix2] = (float)f; zbuf[pix2] = z; dist[pix2] = 0.0f; }
        if (c < 3){
            float bb = (c == 0) ? b0 : ((c == 1) ? b1 : b2);
            bary[3*pix2+c] = bb;
        }
    }
}

extern "C" void kernel_launch(void* const* d_in, const int* in_sizes, int n_in,
                              void* d_out, int out_size, void* d_ws, size_t ws_size,
                              hipStream_t stream) {
    const float* positions = (const float*)d_in[0];
    const float* features  = (const float*)d_in[1];
    const int*   faces     = (const int*)  d_in[2];
    const float* K         = (const float*)d_in[3];
    const float* RT        = (const float*)d_in[4];
    int Fn = in_sizes[2] / 3;   // 16384

    // Workspace: keys cleared by k_pre; one small 0x00 memset covers
    // hist | histcur | gbb(4, all-atomicMax encoding) | tilecnt(144).
    ull*      keys     = (ull*)d_ws;                    // H*W * 8 B
    unsigned* hist     = (unsigned*)(keys + H_*W_);     // 256 words
    unsigned* histcur  = hist + NBUCKET;                // 256 words
    unsigned* gbb      = histcur + NBUCKET;             // 4 words
    unsigned* tilecnt  = gbb + 4;                       // 144 words
    float*    suffz    = (float*)(tilecnt + NTILES);    // 64 floats (scatter blk0)
    float*    rec      = suffz + MAXCHUNK;              // Fn*20 floats (depth-sorted)
    float*    rec0     = rec + (size_t)Fn*20;           // Fn*12 floats (unsorted)

    size_t regB = (NBUCKET*2 + 4 + NTILES)*4;
    hipMemsetAsync(hist, 0x00, regB, stream);

    int nfb = (Fn + 255) / 256;
    k_pre<<<(Fn+63)/64, 64, 0, stream>>>(positions, K, RT, faces, rec0, hist, gbb, keys, Fn);
    k_scatter<<<nfb, 256, 0, stream>>>(rec0, hist, histcur, rec, suffz, Fn);
    dim3 rg(NTX, NTY, NSLICE);
    k_raster<<<rg, dim3(256,1,1), 0, stream>>>(rec, suffz, gbb, keys, tilecnt,
                                               rec0, features, faces, (float*)d_out, Fn);
}

// Round 8
// 174.955 us; speedup vs baseline: 1.4602x; 1.4602x over previous
//
#include <hip/hip_runtime.h>
#include <stdint.h>

#define H_ 192
#define W_ 192
#define C_ 64
#define EPS_F 1e-8f
#define TILE 16
#define NTX (W_/TILE)
#define NTY (H_/TILE)
#define CHUNK 256
#define NSLICE 8
#define NBUCKET 256
#define MAXCHUNK 64

typedef unsigned long long ull;

// Output layout (floats), concatenated in reference return order:
// feats (H*W*C) | p2f (H*W) | zbuf (H*W) | bary (H*W*3) | dists (H*W)
#define OFF_FEATS 0
#define OFF_P2F   (H_*W_*C_)
#define OFF_ZBUF  (OFF_P2F + H_*W_)
#define OFF_BARY  (OFF_ZBUF + H_*W_)
#define OFF_DIST  (OFF_BARY + H_*W_*3)

// IEEE-exact ops (block FMA contraction; match numpy float32 op-for-op)
__device__ __forceinline__ float xm(float a, float b){ return __fmul_rn(a,b); }
__device__ __forceinline__ float xa(float a, float b){ return __fadd_rn(a,b); }
__device__ __forceinline__ float xsb(float a, float b){ return __fsub_rn(a,b); }
__device__ __forceinline__ float xd(float a, float b){ return __fdiv_rn(a,b); }

__device__ __forceinline__ float pixcoord(int i, float dim){
    float t = xa(xm(2.0f, (float)i), 1.0f);
    return xsb(1.0f, xd(t, dim));
}

// monotone float<->uint encode (order-preserving). Identity for atomicMax is 0.
// min(x) is tracked as max(fenc(-x)): ALL four bbox trackers init to 0x00000000.
__device__ __forceinline__ unsigned fenc(float f){
    unsigned b = __float_as_uint(f);
    return (b & 0x80000000u) ? ~b : (b | 0x80000000u);
}
__device__ __forceinline__ float fdec(unsigned e){
    unsigned b = (e & 0x80000000u) ? (e & 0x7FFFFFFFu) : ~e;
    return __uint_as_float(b);
}

// depth bucket: fixed mapping. zlo(b) below must lower-bound every zmin in b.
__device__ __forceinline__ int zbucket(float zmn){
    int b = (int)((zmn - 2.0f) * 64.0f);
    return b < 0 ? 0 : (b > 254 ? 254 : b);
}
__device__ __forceinline__ float zlo_bucket(int b){
    if (b >= 255) return INFINITY;      // dead bucket (or beyond end)
    if (b == 0)   return 0.0f;          // bucket 0 catches all small z
    return 2.0f + (float)b * 0.015625f; // faces in b have zmin >= 2 + b/64
}

// Vertex transform — computed ONCE (k_pre); consumers read the stored bits.
__device__ __forceinline__ float3 tv(const float* __restrict__ pos,
        const float* __restrict__ K, const float* __restrict__ RT, int i){
    float p0 = pos[3*i+0], p1 = pos[3*i+1], p2 = pos[3*i+2];
    const float sgn[3] = {-1.f, -1.f, 1.f};
    float vv[3];
    #pragma unroll
    for (int j=0;j<3;j++){
        float rp0 = xm(RT[j*4+0], sgn[j]);
        float rp1 = xm(RT[j*4+1], sgn[j]);
        float rp2 = xm(RT[j*4+2], sgn[j]);
        float s = xa(xa(xm(p0,rp0), xm(p1,rp1)), xm(p2,rp2));
        vv[j] = xa(s, xm(RT[j*4+3], sgn[j]));
    }
    float z = vv[2];
    float fx = xd(K[0], 96.0f);
    float fy = xd(K[4], 96.0f);
    float p0x = -xd(xsb(K[2], 96.0f), 96.0f);
    float p0y = -xd(xsb(K[5], 96.0f), 96.0f);
    float xn = xa(xd(xm(fx, vv[0]), z), p0x);
    float yn = xa(xd(xm(fy, vv[1]), z), p0y);
    return make_float3(xn, yn, z);
}

// Launch 2 of 5 (256 blocks x 64 thr): transform verts once, write unsorted
// record rec0[f], LDS histogram -> non-returning global adds, wave-reduced
// bbox (all-atomicMax), and grid-stride clear of keys (replaces big memset).
// rec0 (3 float4): q0 x0,y0,x1,y1 | q1 x2,y2,z0,z1 | q2 z2,ia,fid,zmin
__global__ __launch_bounds__(64) void k_pre(const float* __restrict__ pos,
        const float* __restrict__ K, const float* __restrict__ RT,
        const int* __restrict__ faces, float* __restrict__ rec0,
        unsigned* __restrict__ hist, unsigned* __restrict__ gbb,
        ull* __restrict__ keys, int Fn){
    __shared__ unsigned lh[NBUCKET];
    int t = threadIdx.x, B = blockIdx.x;
    int gthreads = gridDim.x*64;
    for (int i = B*64 + t; i < H_*W_; i += gthreads) keys[i] = 0xFFFFFFFFFFFFFFFFULL;
    #pragma unroll
    for (int i=t; i<NBUCKET; i+=64) lh[i] = 0u;
    __syncthreads();
    int f = B*64 + t;
    float bxmn=INFINITY, bxmx=-INFINITY, bymn=INFINITY, bymx=-INFINITY;
    if (f < Fn){
        int i0 = faces[3*f+0], i1 = faces[3*f+1], i2 = faces[3*f+2];
        float3 v0 = tv(pos,K,RT,i0), v1 = tv(pos,K,RT,i1), v2 = tv(pos,K,RT,i2);
        float area = xsb(xm(xsb(v1.x,v0.x), xsb(v2.y,v0.y)), xm(xsb(v1.y,v0.y), xsb(v2.x,v0.x)));
        bool ok = (area > EPS_F) && (v0.z > 0.f) && (v1.z > 0.f) && (v2.z > 0.f);
        float ia = ok ? xd(1.0f, area) : 0.0f;
        float zmn = INFINITY;
        int b = 255;
        if (ok){
            zmn = fminf(v0.z, fminf(v1.z, v2.z));
            b = zbucket(zmn);
            bxmn = fminf(v0.x, fminf(v1.x, v2.x)) - 1e-4f;
            bxmx = fmaxf(v0.x, fmaxf(v1.x, v2.x)) + 1e-4f;
            bymn = fminf(v0.y, fminf(v1.y, v2.y)) - 1e-4f;
            bymx = fmaxf(v0.y, fmaxf(v1.y, v2.y)) + 1e-4f;
        }
        atomicAdd(&lh[b], 1u);
        float4* q = (float4*)(rec0 + (size_t)f*12);
        q[0] = make_float4(v0.x, v0.y, v1.x, v1.y);
        q[1] = make_float4(v2.x, v2.y, v0.z, v1.z);
        q[2] = make_float4(v2.z, ia, __int_as_float(f), zmn);
    }
    // single-wave bbox reduce -> 4 non-returning atomics per block
    #pragma unroll
    for (int s2=1; s2<64; s2<<=1){
        bxmn = fminf(bxmn, __shfl_xor(bxmn, s2, 64));
        bxmx = fmaxf(bxmx, __shfl_xor(bxmx, s2, 64));
        bymn = fminf(bymn, __shfl_xor(bymn, s2, 64));
        bymx = fmaxf(bymx, __shfl_xor(bymx, s2, 64));
    }
    if (t == 0 && bxmx > -INFINITY){   // skip all-dead blocks
        atomicMax(&gbb[0], fenc(-bxmn));   // min x  as max of fenc(-x)
        atomicMax(&gbb[1], fenc( bxmx));
        atomicMax(&gbb[2], fenc(-bymn));
        atomicMax(&gbb[3], fenc( bymx));
    }
    __syncthreads();
    #pragma unroll
    for (int i=t; i<NBUCKET; i+=64){
        unsigned cc = lh[i];
        if (cc) atomicAdd(&hist[i], cc);   // non-returning, <=256 contenders
    }
}

// Launch 3 of 5 (64 blocks x 256): read summed hist, LDS scan, LDS-rank +
// one returning global atomic per (block,bucket), permute rec0 -> depth-sorted
// rec. Block 0 derives analytic chunk z-bounds suffz[] from the scan.
// rec: q0 x0,y0,x1,y1 | q1 x2,y2,z0,z1 | q2 z2,ia,fid,zmin | q3 A,B,C,0 | q4 xmn,xmx,ymn,ymx
__global__ __launch_bounds__(256) void k_scatter(const float* __restrict__ rec0,
        const unsigned* __restrict__ hist, unsigned* __restrict__ histcur,
        float* __restrict__ rec, float* __restrict__ suffz, int Fn){
    __shared__ unsigned gst[NBUCKET], ssc[NBUCKET], lcnt[NBUCKET], lbase[NBUCKET];
    int t = threadIdx.x, B = blockIdx.x;
    unsigned hv = hist[t];
    ssc[t] = hv;
    lcnt[t] = 0u;
    __syncthreads();
    for (int d=1; d<NBUCKET; d<<=1){
        unsigned u = (t >= d) ? ssc[t-d] : 0u;
        __syncthreads();
        ssc[t] += u;
        __syncthreads();
    }
    gst[t] = ssc[t] - hv;   // exclusive global bucket start
    __syncthreads();
    // Block 0: suffz[c] = zlo(bucket containing sorted position c*CHUNK).
    // Buckets ascend in z, so this is simultaneously the suffix-min bound.
    if (B == 0 && t < MAXCHUNK){
        unsigned pos = (unsigned)t * CHUNK;
        int bb = 0;
        #pragma unroll
        for (int s = 128; s > 0; s >>= 1){
            int nb = bb + s;
            if (nb <= NBUCKET && ssc[nb-1] <= pos) bb = nb;
        }
        suffz[t] = zlo_bucket(bb);   // bb==256 (pos>=Fn) -> INF via >=255
    }
    int f = B*256 + t;
    bool valid = (f < Fn);
    float4 q0, q1, q2;
    int b = 255; unsigned rank = 0; bool ok = false; float zmn = INFINITY;
    if (valid){
        const float4* q = (const float4*)(rec0 + (size_t)f*12);
        q0 = q[0]; q1 = q[1]; q2 = q[2];
        ok = (q2.y > 0.f);            // ia > 0 <=> face live
        zmn = q2.w;
        b = ok ? zbucket(zmn) : 255;
        rank = atomicAdd(&lcnt[b], 1u);     // LDS intra-block rank
    }
    __syncthreads();
    unsigned add = lcnt[t];
    if (add) lbase[t] = atomicAdd(&histcur[t], add);  // one per (block,bucket)
    __syncthreads();
    if (valid){
        float x0=q0.x, y0=q0.y, x1=q0.z, y1=q0.w;
        float x2=q1.x, y2=q1.y, z0=q1.z, z1=q1.w;
        float z2=q2.x, ia=q2.y;
        float xmn, xmx, ymn, ymx, Ap=0.f, Bp=0.f, Cp=0.f;
        if (ok){
            xmn = fminf(x0, fminf(x1, x2)) - 1e-4f;
            xmx = fmaxf(x0, fmaxf(x1, x2)) + 1e-4f;
            ymn = fminf(y0, fminf(y1, y2)) - 1e-4f;
            ymx = fmaxf(y0, fmaxf(y1, y2)) + 1e-4f;
            // 1/zp = C + A*px + B*py  (filter-only; margins absorb FP error)
            float iz0 = 1.f/z0, iz1 = 1.f/z1, iz2 = 1.f/z2;
            Ap = ia * ((y1-y2)*iz0 + (y2-y0)*iz1 + (y0-y1)*iz2);
            Bp = ia * ((x2-x1)*iz0 + (x0-x2)*iz1 + (x1-x0)*iz2);
            Cp = ia * ((x1*y2-x2*y1)*iz0 + (x2*y0-x0*y2)*iz1 + (x0*y1-x1*y0)*iz2);
        } else {
            xmn = INFINITY; xmx = -INFINITY; ymn = INFINITY; ymx = -INFINITY;
        }
        unsigned p = gst[b] + lbase[b] + rank;   // unique depth-sorted slot
        float4* qo = (float4*)(rec + (size_t)p*20);
        qo[0] = q0; qo[1] = q1; qo[2] = q2;
        qo[3] = make_float4(Ap, Bp, Cp, 0.f);
        qo[4] = make_float4(xmn, xmx, ymn, ymx);
    }
}

// Launch 4 of 5: tiled raster (1152 blocks). All skips provably conservative
// vs the FINAL key (zcut >= final zbest always) -> timing-independent output.
// NEW: monotone bucket-floor wave-break in the survivor loop. Survivor order
// (compaction is order-preserving; sorted positions ascend in bucket) makes
// zfs[] a lower bound for slot k AND all later slots -> __all break is exact.
__global__ __launch_bounds__(256) void k_raster(const float* __restrict__ rec,
        const float* __restrict__ suffz, const unsigned* __restrict__ gbb,
        ull* __restrict__ keys, int Fn){
    __shared__ float lds[CHUNK*12];
    __shared__ float zl[CHUNK];       // per-tile z lower bound of survivors
    __shared__ float zfs[CHUNK];      // bucket-floor of survivors (monotone)
    __shared__ int   slist[CHUNK];
    __shared__ int   wcnt[4];
    __shared__ float suff[MAXCHUNK];  // analytic chunk z-bounds (already suffix-min)
    int tid = threadIdx.x;
    int nchunk = (Fn + CHUNK - 1) / CHUNK;
    if (tid < MAXCHUNK) suff[tid] = suffz[tid];
    int ix = blockIdx.x*TILE + (tid & 15);
    int iy = blockIdx.y*TILE + (tid >> 4);
    int pix = iy*W_ + ix;
    float px = pixcoord(ix, (float)W_);
    float py = pixcoord(iy, (float)H_);
    float tx_hi = pixcoord(blockIdx.x*TILE,          (float)W_);
    float tx_lo = pixcoord(blockIdx.x*TILE + TILE-1, (float)W_);
    float ty_hi = pixcoord(blockIdx.y*TILE,          (float)H_);
    float ty_lo = pixcoord(blockIdx.y*TILE + TILE-1, (float)H_);
    float gx0 = -fdec(gbb[0]), gx1 = fdec(gbb[1]);   // NaN (no live faces) -> alive=false
    float gy0 = -fdec(gbb[2]), gy1 = fdec(gbb[3]);
    bool alive = (px >= gx0) && (px <= gx1) && (py >= gy0) && (py <= gy1);
    int lane = tid & 63, wv = tid >> 6;

    float zcut = INFINITY;
    ull localkey = 0xFFFFFFFFFFFFFFFFULL;
    ull published = 0xFFFFFFFFFFFFFFFFULL;
    __syncthreads();             // suff[] ready

    for (int c = (int)blockIdx.z; c < nchunk; c += NSLICE){
        // share depth convergence across slice blocks (stale reads conservative)
        ull g = __hip_atomic_load(&keys[pix], __ATOMIC_RELAXED, __HIP_MEMORY_SCOPE_AGENT);
        float zg = __uint_as_float((unsigned)(g >> 32));   // NaN if empty -> fminf ignores
        zcut = fminf(zcut, zg);
        float sc = (c < MAXCHUNK) ? suff[c] : 0.0f;
        int done = (!alive || !(xm(sc, 0.999f) < zcut)) ? 1 : 0;
        if (__syncthreads_and(done)) break;    // barrier also protects lds reuse

        int fi = c*CHUNK + tid;
        float4 q0 = make_float4(0,0,0,0), q1 = q0, q2 = q0;
        bool keep = false;
        float zb = 0.f, zf = 0.f;
        if (fi < Fn){
            const float4* gq = (const float4*)(rec + (size_t)fi*20);
            q0 = gq[0]; q1 = gq[1]; q2 = gq[2];
            float4 q3 = gq[3], q4 = gq[4];
            keep = (q4.x <= tx_hi) && (q4.y >= tx_lo) && (q4.z <= ty_hi) && (q4.w >= ty_lo);
            if (keep){
                // tile z lower bound from the linear 1/z plane (corner max + margin)
                float ax = (q3.x > 0.f) ? tx_hi : tx_lo;
                float by = (q3.y > 0.f) ? ty_hi : ty_lo;
                float Nmax = q3.z + q3.x*ax + q3.y*by;
                float M = fabsf(q3.x*ax) + fabsf(q3.y*by) + fabsf(q3.z);
                float Nub = Nmax + 1e-5f*M + 1e-30f;
                if (Nub <= 0.f) keep = false;          // no coverage possible in tile
                else {
                    zf = zlo_bucket(zbucket(q2.w));    // monotone-in-slot floor
                    zb = fmaxf(fmaxf(1.f/Nub, q2.w), zf); // tile bound (per-lane filter)
                }
            }
        }
        float4* l = (float4*)(lds + tid*12);
        l[0] = q0; l[1] = q1; l[2] = q2;
        ull m = __ballot(keep);
        if (lane == 0) wcnt[wv] = __popcll(m);
        __syncthreads();
        int basecnt = 0;
        #pragma unroll
        for (int w2 = 0; w2 < 4; ++w2) if (w2 < wv) basecnt += wcnt[w2];
        if (keep){
            int p = basecnt + __popcll(m & ((1ULL << lane) - 1ULL));
            slist[p] = tid;
            zl[p] = zb;
            zfs[p] = zf;
        }
        int nsurv = wcnt[0] + wcnt[1] + wcnt[2] + wcnt[3];
        __syncthreads();

        for (int k = 0; k < nsurv; k++){
            // monotone break: zfs ascends with k (bucket order), so if every
            // lane's zcut already beats this floor, no later k can win. Wave-
            // uniform break (no barrier inside loop; LDS is read-only here).
            float zfl = zfs[k];
            if (__all(!(xm(zfl, 0.999f) < zcut))) break;
            float zbl = zl[k];
            if (!(xm(zbl, 0.999f) < zcut)) continue;   // per-lane tile-z precheck
            int j = slist[k];
            const float* r = lds + j*12;
            float x0=r[0], y0=r[1], x1=r[2], y1=r[3], x2=r[4], y2=r[5];
            float dx0=xsb(x0,px), dx1=xsb(x1,px), dx2=xsb(x2,px);
            float dy0=xsb(y0,py), dy1=xsb(y1,py), dy2=xsb(y2,py);
            float e0 = xsb(xm(dx1,dy2), xm(dy1,dx2));
            float e1 = xsb(xm(dx2,dy0), xm(dy2,dx0));
            float e2 = xsb(xm(dx0,dy1), xm(dy0,dx1));
            if (e0 >= 0.f && e1 >= 0.f && e2 >= 0.f){
                float z0=r[6], z1=r[7], z2=r[8], ia=r[9];
                float w0 = xm(e0, ia), w1 = xm(e1, ia), w2 = xm(e2, ia);
                float l0 = xm(xm(w0,z1),z2);
                float l1 = xm(xm(z0,w1),z2);
                float l2 = xm(xm(z0,z1),w2);
                float s  = xa(xa(l0,l1),l2);
                // cheap-z filter (1 divide); skip only when provably worse than zcut.
                float za = (l0*z0 + l1*z1 + l2*z2) / s;
                if (za*0.99999f >= zcut) continue;
                float dn = (s == 0.f) ? 1.0f : s;
                float b0 = fmaxf(xd(l0,dn), 0.f);
                float b1 = fmaxf(xd(l1,dn), 0.f);
                float b2 = fmaxf(xd(l2,dn), 0.f);
                float bs = fmaxf(xa(xa(b0,b1),b2), EPS_F);
                b0 = xd(b0,bs); b1 = xd(b1,bs); b2 = xd(b2,bs);
                float zp = xa(xa(xm(b0,z0),xm(b1,z1)),xm(b2,z2));
                // packed (z, orig_fid) key: exact argmin-first tie semantics
                ull ck = (((ull)__float_as_uint(zp)) << 32) | (unsigned)__float_as_int(r[10]);
                if (ck < localkey) localkey = ck;
                zcut = fminf(zcut, zp);
            }
        }
        if (localkey < published){     // publish so other slice blocks can break
            atomicMin(&keys[pix], localkey);
            published = localkey;
        }
    }
    if (localkey < published) atomicMin(&keys[pix], localkey);
}

// Launch 5 of 5: resolve + shade; 64 lanes per pixel (lane = channel),
// 4 pixels/block, 9216 blocks — TLP hides the gather chains (r7 lesson:
// fusing this into raster's 144 tail blocks was 5x slower).
__global__ __launch_bounds__(256) void k_post(const ull* __restrict__ keys,
        const float* __restrict__ rec0, const float* __restrict__ feats,
        const int* __restrict__ faces, float* __restrict__ out){
    int grp = threadIdx.x >> 6;
    int c = threadIdx.x & 63;
    int pix = blockIdx.x*4 + grp;
    float* p2f  = out + OFF_P2F;
    float* zbuf = out + OFF_ZBUF;
    float* bary = out + OFF_BARY;
    float* dist = out + OFF_DIST;
    ull key = keys[pix];
    if (key == 0xFFFFFFFFFFFFFFFFULL){
        out[OFF_FEATS + pix*C_ + c] = 0.0f;
        if (c == 0){
            p2f[pix] = -1.0f; zbuf[pix] = -1.0f; dist[pix] = -1.0f;
        }
        if (c < 3) bary[3*pix+c] = -1.0f;
        return;
    }
    int f = (int)(key & 0xFFFFFFFFu);
    float z = __uint_as_float((unsigned)(key >> 32));
    int ix = pix % W_, iy = pix / W_;
    float px = pixcoord(ix, (float)W_);
    float py = pixcoord(iy, (float)H_);
    const float4* q = (const float4*)(rec0 + (size_t)f*12);
    float4 q0 = q[0], q1 = q[1], q2 = q[2];
    float x0=q0.x, y0=q0.y, x1=q0.z, y1=q0.w;
    float x2=q1.x, y2=q1.y, z0=q1.z, z1=q1.w;
    float z2=q2.x, ia=q2.y;
    float w0 = xm(xsb(xm(xsb(x1,px),xsb(y2,py)), xm(xsb(y1,py),xsb(x2,px))), ia);
    float w1 = xm(xsb(xm(xsb(x2,px),xsb(y0,py)), xm(xsb(y2,py),xsb(x0,px))), ia);
    float w2 = xm(xsb(xm(xsb(x0,px),xsb(y1,py)), xm(xsb(y0,py),xsb(x1,px))), ia);
    float l0 = xm(xm(w0,z1),z2);
    float l1 = xm(xm(z0,w1),z2);
    float l2 = xm(xm(z0,z1),w2);
    float s  = xa(xa(l0,l1),l2);
    float dn = (s == 0.f) ? 1.0f : s;
    float b0 = fmaxf(xd(l0,dn), 0.f);
    float b1 = fmaxf(xd(l1,dn), 0.f);
    float b2 = fmaxf(xd(l2,dn), 0.f);
    float bs = fmaxf(xa(xa(b0,b1),b2), EPS_F);
    b0 = xd(b0,bs); b1 = xd(b1,bs); b2 = xd(b2,bs);
    int i0 = faces[3*f+0], i1 = faces[3*f+1], i2 = faces[3*f+2];
    float res = xa(xa(xm(b0, feats[i0*C_ + c]), xm(b1, feats[i1*C_ + c])),
                   xm(b2, feats[i2*C_ + c]));
    out[OFF_FEATS + pix*C_ + c] = res;
    if (c == 0){
        p2f[pix] = (float)f; zbuf[pix] = z; dist[pix] = 0.0f;
    }
    if (c < 3){
        float bb = (c == 0) ? b0 : ((c == 1) ? b1 : b2);
        bary[3*pix+c] = bb;
    }
}

extern "C" void kernel_launch(void* const* d_in, const int* in_sizes, int n_in,
                              void* d_out, int out_size, void* d_ws, size_t ws_size,
                              hipStream_t stream) {
    const float* positions = (const float*)d_in[0];
    const float* features  = (const float*)d_in[1];
    const int*   faces     = (const int*)  d_in[2];
    const float* K         = (const float*)d_in[3];
    const float* RT        = (const float*)d_in[4];
    int Fn = in_sizes[2] / 3;   // 16384

    // Workspace: keys cleared by k_pre; one small 0x00 memset covers
    // hist | histcur | gbb(4, all-atomicMax encoding).
    ull*      keys     = (ull*)d_ws;                    // H*W * 8 B
    unsigned* hist     = (unsigned*)(keys + H_*W_);     // 256 words
    unsigned* histcur  = hist + NBUCKET;                // 256 words
    unsigned* gbb      = histcur + NBUCKET;             // 4 words
    float*    suffz    = (float*)(gbb + 4);             // 64 floats (scatter blk0)
    float*    rec      = suffz + MAXCHUNK;              // Fn*20 floats (depth-sorted)
    float*    rec0     = rec + (size_t)Fn*20;           // Fn*12 floats (unsorted)

    size_t regB = (NBUCKET*2 + 4)*4;
    hipMemsetAsync(hist, 0x00, regB, stream);

    int nfb = (Fn + 255) / 256;
    k_pre<<<(Fn+63)/64, 64, 0, stream>>>(positions, K, RT, faces, rec0, hist, gbb, keys, Fn);
    k_scatter<<<nfb, 256, 0, stream>>>(rec0, hist, histcur, rec, suffz, Fn);
    dim3 rg(NTX, NTY, NSLICE);
    k_raster<<<rg, dim3(256,1,1), 0, stream>>>(rec, suffz, gbb, keys, Fn);
    k_post<<<(H_*W_)/4, 256, 0, stream>>>(keys, rec0, features, faces, (float*)d_out);
}

// Round 9
// 141.453 us; speedup vs baseline: 1.8061x; 1.2368x over previous
//
#include <hip/hip_runtime.h>
#include <stdint.h>

#define H_ 192
#define W_ 192
#define C_ 64
#define EPS_F 1e-8f
#define TILE 16
#define NTX (W_/TILE)
#define NTY (H_/TILE)
#define CHUNK 256
#define NSLICE 8
#define NBUCKET 256
#define MAXCHUNK 64

typedef unsigned long long ull;

// Output layout (floats), concatenated in reference return order:
// feats (H*W*C) | p2f (H*W) | zbuf (H*W) | bary (H*W*3) | dists (H*W)
#define OFF_FEATS 0
#define OFF_P2F   (H_*W_*C_)
#define OFF_ZBUF  (OFF_P2F + H_*W_)
#define OFF_BARY  (OFF_ZBUF + H_*W_)
#define OFF_DIST  (OFF_BARY + H_*W_*3)

// IEEE-exact ops (block FMA contraction; match numpy float32 op-for-op)
__device__ __forceinline__ float xm(float a, float b){ return __fmul_rn(a,b); }
__device__ __forceinline__ float xa(float a, float b){ return __fadd_rn(a,b); }
__device__ __forceinline__ float xsb(float a, float b){ return __fsub_rn(a,b); }
__device__ __forceinline__ float xd(float a, float b){ return __fdiv_rn(a,b); }

__device__ __forceinline__ float pixcoord(int i, float dim){
    float t = xa(xm(2.0f, (float)i), 1.0f);
    return xsb(1.0f, xd(t, dim));
}

// monotone float<->uint encode (order-preserving). Identity for atomicMax is 0.
// min(x) is tracked as max(fenc(-x)): ALL four bbox trackers init to 0x00000000.
__device__ __forceinline__ unsigned fenc(float f){
    unsigned b = __float_as_uint(f);
    return (b & 0x80000000u) ? ~b : (b | 0x80000000u);
}
__device__ __forceinline__ float fdec(unsigned e){
    unsigned b = (e & 0x80000000u) ? (e & 0x7FFFFFFFu) : ~e;
    return __uint_as_float(b);
}

// depth bucket: fixed mapping. zlo(b) below must lower-bound every zmin in b.
__device__ __forceinline__ int zbucket(float zmn){
    int b = (int)((zmn - 2.0f) * 64.0f);
    return b < 0 ? 0 : (b > 254 ? 254 : b);
}
__device__ __forceinline__ float zlo_bucket(int b){
    if (b >= 255) return INFINITY;      // dead bucket (or beyond end)
    if (b == 0)   return 0.0f;          // bucket 0 catches all small z
    return 2.0f + (float)b * 0.015625f; // faces in b have zmin >= 2 + b/64
}

// Vertex transform — computed ONCE (k_pre); consumers read the stored bits.
__device__ __forceinline__ float3 tv(const float* __restrict__ pos,
        const float* __restrict__ K, const float* __restrict__ RT, int i){
    float p0 = pos[3*i+0], p1 = pos[3*i+1], p2 = pos[3*i+2];
    const float sgn[3] = {-1.f, -1.f, 1.f};
    float vv[3];
    #pragma unroll
    for (int j=0;j<3;j++){
        float rp0 = xm(RT[j*4+0], sgn[j]);
        float rp1 = xm(RT[j*4+1], sgn[j]);
        float rp2 = xm(RT[j*4+2], sgn[j]);
        float s = xa(xa(xm(p0,rp0), xm(p1,rp1)), xm(p2,rp2));
        vv[j] = xa(s, xm(RT[j*4+3], sgn[j]));
    }
    float z = vv[2];
    float fx = xd(K[0], 96.0f);
    float fy = xd(K[4], 96.0f);
    float p0x = -xd(xsb(K[2], 96.0f), 96.0f);
    float p0y = -xd(xsb(K[5], 96.0f), 96.0f);
    float xn = xa(xd(xm(fx, vv[0]), z), p0x);
    float yn = xa(xd(xm(fy, vv[1]), z), p0y);
    return make_float3(xn, yn, z);
}

// Launch 2 of 5 (256 blocks x 64 thr): transform verts once, write unsorted
// record rec0[f], LDS histogram -> non-returning global adds, wave-reduced
// bbox (all-atomicMax), and grid-stride clear of keys (replaces big memset).
// rec0 (3 float4): q0 x0,y0,x1,y1 | q1 x2,y2,z0,z1 | q2 z2,ia,fid,zmin
__global__ __launch_bounds__(64) void k_pre(const float* __restrict__ pos,
        const float* __restrict__ K, const float* __restrict__ RT,
        const int* __restrict__ faces, float* __restrict__ rec0,
        unsigned* __restrict__ hist, unsigned* __restrict__ gbb,
        ull* __restrict__ keys, int Fn){
    __shared__ unsigned lh[NBUCKET];
    int t = threadIdx.x, B = blockIdx.x;
    int gthreads = gridDim.x*64;
    for (int i = B*64 + t; i < H_*W_; i += gthreads) keys[i] = 0xFFFFFFFFFFFFFFFFULL;
    #pragma unroll
    for (int i=t; i<NBUCKET; i+=64) lh[i] = 0u;
    __syncthreads();
    int f = B*64 + t;
    float bxmn=INFINITY, bxmx=-INFINITY, bymn=INFINITY, bymx=-INFINITY;
    if (f < Fn){
        int i0 = faces[3*f+0], i1 = faces[3*f+1], i2 = faces[3*f+2];
        float3 v0 = tv(pos,K,RT,i0), v1 = tv(pos,K,RT,i1), v2 = tv(pos,K,RT,i2);
        float area = xsb(xm(xsb(v1.x,v0.x), xsb(v2.y,v0.y)), xm(xsb(v1.y,v0.y), xsb(v2.x,v0.x)));
        bool ok = (area > EPS_F) && (v0.z > 0.f) && (v1.z > 0.f) && (v2.z > 0.f);
        float ia = ok ? xd(1.0f, area) : 0.0f;
        float zmn = INFINITY;
        int b = 255;
        if (ok){
            zmn = fminf(v0.z, fminf(v1.z, v2.z));
            b = zbucket(zmn);
            bxmn = fminf(v0.x, fminf(v1.x, v2.x)) - 1e-4f;
            bxmx = fmaxf(v0.x, fmaxf(v1.x, v2.x)) + 1e-4f;
            bymn = fminf(v0.y, fminf(v1.y, v2.y)) - 1e-4f;
            bymx = fmaxf(v0.y, fmaxf(v1.y, v2.y)) + 1e-4f;
        }
        atomicAdd(&lh[b], 1u);
        float4* q = (float4*)(rec0 + (size_t)f*12);
        q[0] = make_float4(v0.x, v0.y, v1.x, v1.y);
        q[1] = make_float4(v2.x, v2.y, v0.z, v1.z);
        q[2] = make_float4(v2.z, ia, __int_as_float(f), zmn);
    }
    // single-wave bbox reduce -> 4 non-returning atomics per block
    #pragma unroll
    for (int s2=1; s2<64; s2<<=1){
        bxmn = fminf(bxmn, __shfl_xor(bxmn, s2, 64));
        bxmx = fmaxf(bxmx, __shfl_xor(bxmx, s2, 64));
        bymn = fminf(bymn, __shfl_xor(bymn, s2, 64));
        bymx = fmaxf(bymx, __shfl_xor(bymx, s2, 64));
    }
    if (t == 0 && bxmx > -INFINITY){   // skip all-dead blocks
        atomicMax(&gbb[0], fenc(-bxmn));   // min x  as max of fenc(-x)
        atomicMax(&gbb[1], fenc( bxmx));
        atomicMax(&gbb[2], fenc(-bymn));
        atomicMax(&gbb[3], fenc( bymx));
    }
    __syncthreads();
    #pragma unroll
    for (int i=t; i<NBUCKET; i+=64){
        unsigned cc = lh[i];
        if (cc) atomicAdd(&hist[i], cc);   // non-returning, <=256 contenders
    }
}

// Launch 3 of 5 (64 blocks x 256): read summed hist, LDS scan, LDS-rank +
// one returning global atomic per (block,bucket), permute rec0 -> depth-sorted
// rec. Block 0 derives analytic chunk z-bounds suffz[] from the scan.
// rec: q0 x0,y0,x1,y1 | q1 x2,y2,z0,z1 | q2 z2,ia,fid,zmin | q3 A,B,C,0 | q4 xmn,xmx,ymn,ymx
__global__ __launch_bounds__(256) void k_scatter(const float* __restrict__ rec0,
        const unsigned* __restrict__ hist, unsigned* __restrict__ histcur,
        float* __restrict__ rec, float* __restrict__ suffz, int Fn){
    __shared__ unsigned gst[NBUCKET], ssc[NBUCKET], lcnt[NBUCKET], lbase[NBUCKET];
    int t = threadIdx.x, B = blockIdx.x;
    unsigned hv = hist[t];
    ssc[t] = hv;
    lcnt[t] = 0u;
    __syncthreads();
    for (int d=1; d<NBUCKET; d<<=1){
        unsigned u = (t >= d) ? ssc[t-d] : 0u;
        __syncthreads();
        ssc[t] += u;
        __syncthreads();
    }
    gst[t] = ssc[t] - hv;   // exclusive global bucket start
    __syncthreads();
    // Block 0: suffz[c] = zlo(bucket containing sorted position c*CHUNK).
    // Buckets ascend in z, so this is simultaneously the suffix-min bound.
    if (B == 0 && t < MAXCHUNK){
        unsigned pos = (unsigned)t * CHUNK;
        int bb = 0;
        #pragma unroll
        for (int s = 128; s > 0; s >>= 1){
            int nb = bb + s;
            if (nb <= NBUCKET && ssc[nb-1] <= pos) bb = nb;
        }
        suffz[t] = zlo_bucket(bb);   // bb==256 (pos>=Fn) -> INF via >=255
    }
    int f = B*256 + t;
    bool valid = (f < Fn);
    float4 q0, q1, q2;
    int b = 255; unsigned rank = 0; bool ok = false; float zmn = INFINITY;
    if (valid){
        const float4* q = (const float4*)(rec0 + (size_t)f*12);
        q0 = q[0]; q1 = q[1]; q2 = q[2];
        ok = (q2.y > 0.f);            // ia > 0 <=> face live
        zmn = q2.w;
        b = ok ? zbucket(zmn) : 255;
        rank = atomicAdd(&lcnt[b], 1u);     // LDS intra-block rank
    }
    __syncthreads();
    unsigned add = lcnt[t];
    if (add) lbase[t] = atomicAdd(&histcur[t], add);  // one per (block,bucket)
    __syncthreads();
    if (valid){
        float x0=q0.x, y0=q0.y, x1=q0.z, y1=q0.w;
        float x2=q1.x, y2=q1.y, z0=q1.z, z1=q1.w;
        float z2=q2.x, ia=q2.y;
        float xmn, xmx, ymn, ymx, Ap=0.f, Bp=0.f, Cp=0.f;
        if (ok){
            xmn = fminf(x0, fminf(x1, x2)) - 1e-4f;
            xmx = fmaxf(x0, fmaxf(x1, x2)) + 1e-4f;
            ymn = fminf(y0, fminf(y1, y2)) - 1e-4f;
            ymx = fmaxf(y0, fmaxf(y1, y2)) + 1e-4f;
            // 1/zp = C + A*px + B*py  (filter-only; margins absorb FP error)
            float iz0 = 1.f/z0, iz1 = 1.f/z1, iz2 = 1.f/z2;
            Ap = ia * ((y1-y2)*iz0 + (y2-y0)*iz1 + (y0-y1)*iz2);
            Bp = ia * ((x2-x1)*iz0 + (x0-x2)*iz1 + (x1-x0)*iz2);
            Cp = ia * ((x1*y2-x2*y1)*iz0 + (x2*y0-x0*y2)*iz1 + (x0*y1-x1*y0)*iz2);
        } else {
            xmn = INFINITY; xmx = -INFINITY; ymn = INFINITY; ymx = -INFINITY;
        }
        unsigned p = gst[b] + lbase[b] + rank;   // unique depth-sorted slot
        float4* qo = (float4*)(rec + (size_t)p*20);
        qo[0] = q0; qo[1] = q1; qo[2] = q2;
        qo[3] = make_float4(Ap, Bp, Cp, 0.f);
        qo[4] = make_float4(xmn, xmx, ymn, ymx);
    }
}

// Launch 4 of 5: tiled raster (1152 blocks). All skips provably conservative
// vs the FINAL key (zcut >= final zbest for live candidates at all times)
// -> timing-independent output.
// r8 lesson reverted: within-chunk monotone break was redundant with the
// chunk-level suffz break and taxed every iteration. NEW this round: the
// per-survivor skip walk is batched 64-wide — one stride-1 LDS read + one
// ballot tests 64 survivors against zcmax (wave-max of zcut), and the wave
// visits only surviving bits. Skips drop from O(nsurv) serial to O(nsurv/64).
__global__ __launch_bounds__(256) void k_raster(const float* __restrict__ rec,
        const float* __restrict__ suffz, const unsigned* __restrict__ gbb,
        ull* __restrict__ keys, int Fn){
    __shared__ float lds[CHUNK*12];
    __shared__ float zl[CHUNK];       // per-tile z lower bound of survivors
    __shared__ int   slist[CHUNK];
    __shared__ int   wcnt[4];
    __shared__ float suff[MAXCHUNK];  // analytic chunk z-bounds (already suffix-min)
    int tid = threadIdx.x;
    int nchunk = (Fn + CHUNK - 1) / CHUNK;
    if (tid < MAXCHUNK) suff[tid] = suffz[tid];
    int ix = blockIdx.x*TILE + (tid & 15);
    int iy = blockIdx.y*TILE + (tid >> 4);
    int pix = iy*W_ + ix;
    float px = pixcoord(ix, (float)W_);
    float py = pixcoord(iy, (float)H_);
    float tx_hi = pixcoord(blockIdx.x*TILE,          (float)W_);
    float tx_lo = pixcoord(blockIdx.x*TILE + TILE-1, (float)W_);
    float ty_hi = pixcoord(blockIdx.y*TILE,          (float)H_);
    float ty_lo = pixcoord(blockIdx.y*TILE + TILE-1, (float)H_);
    float gx0 = -fdec(gbb[0]), gx1 = fdec(gbb[1]);   // NaN (no live faces) -> alive=false
    float gy0 = -fdec(gbb[2]), gy1 = fdec(gbb[3]);
    bool alive = (px >= gx0) && (px <= gx1) && (py >= gy0) && (py <= gy1);
    int lane = tid & 63, wv = tid >> 6;

    // Dead lanes (outside union of padded face bboxes) can never be hit:
    // zcut=-INF makes them skip all evals AND not inflate the wave zcmax.
    float zcut = alive ? INFINITY : -INFINITY;
    ull localkey = 0xFFFFFFFFFFFFFFFFULL;
    ull published = 0xFFFFFFFFFFFFFFFFULL;
    __syncthreads();             // suff[] ready

    for (int c = (int)blockIdx.z; c < nchunk; c += NSLICE){
        // share depth convergence across slice blocks (stale reads conservative)
        ull g = __hip_atomic_load(&keys[pix], __ATOMIC_RELAXED, __HIP_MEMORY_SCOPE_AGENT);
        float zg = __uint_as_float((unsigned)(g >> 32));   // NaN if empty -> fminf ignores
        zcut = fminf(zcut, zg);
        float sc = (c < MAXCHUNK) ? suff[c] : 0.0f;
        int done = (!alive || !(xm(sc, 0.999f) < zcut)) ? 1 : 0;
        if (__syncthreads_and(done)) break;    // barrier also protects lds reuse

        int fi = c*CHUNK + tid;
        float4 q0 = make_float4(0,0,0,0), q1 = q0, q2 = q0;
        bool keep = false;
        float zb = 0.f;
        if (fi < Fn){
            const float4* gq = (const float4*)(rec + (size_t)fi*20);
            q0 = gq[0]; q1 = gq[1]; q2 = gq[2];
            float4 q3 = gq[3], q4 = gq[4];
            keep = (q4.x <= tx_hi) && (q4.y >= tx_lo) && (q4.z <= ty_hi) && (q4.w >= ty_lo);
            if (keep){
                // tile z lower bound from the linear 1/z plane (corner max + margin)
                float ax = (q3.x > 0.f) ? tx_hi : tx_lo;
                float by = (q3.y > 0.f) ? ty_hi : ty_lo;
                float Nmax = q3.z + q3.x*ax + q3.y*by;
                float M = fabsf(q3.x*ax) + fabsf(q3.y*by) + fabsf(q3.z);
                float Nub = Nmax + 1e-5f*M + 1e-30f;
                if (Nub <= 0.f) keep = false;          // no coverage possible in tile
                else zb = fmaxf(1.f/Nub, q2.w);        // max(plane bound, face zmin)
            }
        }
        float4* l = (float4*)(lds + tid*12);
        l[0] = q0; l[1] = q1; l[2] = q2;
        ull m = __ballot(keep);
        if (lane == 0) wcnt[wv] = __popcll(m);
        __syncthreads();
        int basecnt = 0;
        #pragma unroll
        for (int w2 = 0; w2 < 4; ++w2) if (w2 < wv) basecnt += wcnt[w2];
        if (keep){
            int p = basecnt + __popcll(m & ((1ULL << lane) - 1ULL));
            slist[p] = tid;
            zl[p] = zb;
        }
        int nsurv = wcnt[0] + wcnt[1] + wcnt[2] + wcnt[3];
        __syncthreads();

        // zcmax: wave-max of zcut, fixed for this chunk (stale = conservative:
        // zcut only decreases, so skips vs zcmax are skips vs a valid upper bd).
        float zcmax = zcut;
        #pragma unroll
        for (int s2=1; s2<64; s2<<=1) zcmax = fmaxf(zcmax, __shfl_xor(zcmax, s2, 64));

        for (int k0 = 0; k0 < nsurv; k0 += 64){
            int kk = k0 + lane;
            float zlk = (kk < nsurv) ? zl[kk] : INFINITY;   // stride-1, conflict-free
            ull wm = __ballot(xm(zlk, 0.999f) < zcmax);     // survivors any lane may need
            while (wm){
                int k = (int)__ffsll(wm) - 1;               // ascending k preserves order
                wm &= wm - 1;
                k += k0;
                float zbl = zl[k];                           // uniform addr: broadcast
                if (xm(zbl, 0.999f) < zcut){                 // per-lane precheck
                    int j = slist[k];
                    const float* r = lds + j*12;
                    float x0=r[0], y0=r[1], x1=r[2], y1=r[3], x2=r[4], y2=r[5];
                    float dx0=xsb(x0,px), dx1=xsb(x1,px), dx2=xsb(x2,px);
                    float dy0=xsb(y0,py), dy1=xsb(y1,py), dy2=xsb(y2,py);
                    float e0 = xsb(xm(dx1,dy2), xm(dy1,dx2));
                    float e1 = xsb(xm(dx2,dy0), xm(dy2,dx0));
                    float e2 = xsb(xm(dx0,dy1), xm(dy0,dx1));
                    if (e0 >= 0.f && e1 >= 0.f && e2 >= 0.f){
                        float z0=r[6], z1=r[7], z2=r[8], ia=r[9];
                        float w0 = xm(e0, ia), w1 = xm(e1, ia), w2 = xm(e2, ia);
                        float l0 = xm(xm(w0,z1),z2);
                        float l1 = xm(xm(z0,w1),z2);
                        float l2 = xm(xm(z0,z1),w2);
                        float s  = xa(xa(l0,l1),l2);
                        // cheap-z filter (1 divide); skip only if provably worse.
                        float za = (l0*z0 + l1*z1 + l2*z2) / s;
                        if (za*0.99999f < zcut){
                            float dn = (s == 0.f) ? 1.0f : s;
                            float b0 = fmaxf(xd(l0,dn), 0.f);
                            float b1 = fmaxf(xd(l1,dn), 0.f);
                            float b2 = fmaxf(xd(l2,dn), 0.f);
                            float bs = fmaxf(xa(xa(b0,b1),b2), EPS_F);
                            b0 = xd(b0,bs); b1 = xd(b1,bs); b2 = xd(b2,bs);
                            float zp = xa(xa(xm(b0,z0),xm(b1,z1)),xm(b2,z2));
                            // packed (z, orig_fid) key: exact argmin-first ties
                            ull ck = (((ull)__float_as_uint(zp)) << 32) | (unsigned)__float_as_int(r[10]);
                            if (ck < localkey) localkey = ck;
                            zcut = fminf(zcut, zp);
                        }
                    }
                }
            }
        }
        if (localkey < published){     // publish so other slice blocks can break
            atomicMin(&keys[pix], localkey);
            published = localkey;
        }
    }
    if (localkey < published) atomicMin(&keys[pix], localkey);
}

// Launch 5 of 5: resolve + shade; 64 lanes per pixel (lane = channel),
// 4 pixels/block, 9216 blocks — TLP hides the gather chains (r7 lesson:
// fusing this into raster's 144 tail blocks was 5x slower).
__global__ __launch_bounds__(256) void k_post(const ull* __restrict__ keys,
        const float* __restrict__ rec0, const float* __restrict__ feats,
        const int* __restrict__ faces, float* __restrict__ out){
    int grp = threadIdx.x >> 6;
    int c = threadIdx.x & 63;
    int pix = blockIdx.x*4 + grp;
    float* p2f  = out + OFF_P2F;
    float* zbuf = out + OFF_ZBUF;
    float* bary = out + OFF_BARY;
    float* dist = out + OFF_DIST;
    ull key = keys[pix];
    if (key == 0xFFFFFFFFFFFFFFFFULL){
        out[OFF_FEATS + pix*C_ + c] = 0.0f;
        if (c == 0){
            p2f[pix] = -1.0f; zbuf[pix] = -1.0f; dist[pix] = -1.0f;
        }
        if (c < 3) bary[3*pix+c] = -1.0f;
        return;
    }
    int f = (int)(key & 0xFFFFFFFFu);
    float z = __uint_as_float((unsigned)(key >> 32));
    int ix = pix % W_, iy = pix / W_;
    float px = pixcoord(ix, (float)W_);
    float py = pixcoord(iy, (float)H_);
    const float4* q = (const float4*)(rec0 + (size_t)f*12);
    float4 q0 = q[0], q1 = q[1], q2 = q[2];
    float x0=q0.x, y0=q0.y, x1=q0.z, y1=q0.w;
    float x2=q1.x, y2=q1.y, z0=q1.z, z1=q1.w;
    float z2=q2.x, ia=q2.y;
    float w0 = xm(xsb(xm(xsb(x1,px),xsb(y2,py)), xm(xsb(y1,py),xsb(x2,px))), ia);
    float w1 = xm(xsb(xm(xsb(x2,px),xsb(y0,py)), xm(xsb(y2,py),xsb(x0,px))), ia);
    float w2 = xm(xsb(xm(xsb(x0,px),xsb(y1,py)), xm(xsb(y0,py),xsb(x1,px))), ia);
    float l0 = xm(xm(w0,z1),z2);
    float l1 = xm(xm(z0,w1),z2);
    float l2 = xm(xm(z0,z1),w2);
    float s  = xa(xa(l0,l1),l2);
    float dn = (s == 0.f) ? 1.0f : s;
    float b0 = fmaxf(xd(l0,dn), 0.f);
    float b1 = fmaxf(xd(l1,dn), 0.f);
    float b2 = fmaxf(xd(l2,dn), 0.f);
    float bs = fmaxf(xa(xa(b0,b1),b2), EPS_F);
    b0 = xd(b0,bs); b1 = xd(b1,bs); b2 = xd(b2,bs);
    int i0 = faces[3*f+0], i1 = faces[3*f+1], i2 = faces[3*f+2];
    float res = xa(xa(xm(b0, feats[i0*C_ + c]), xm(b1, feats[i1*C_ + c])),
                   xm(b2, feats[i2*C_ + c]));
    out[OFF_FEATS + pix*C_ + c] = res;
    if (c == 0){
        p2f[pix] = (float)f; zbuf[pix] = z; dist[pix] = 0.0f;
    }
    if (c < 3){
        float bb = (c == 0) ? b0 : ((c == 1) ? b1 : b2);
        bary[3*pix+c] = bb;
    }
}

extern "C" void kernel_launch(void* const* d_in, const int* in_sizes, int n_in,
                              void* d_out, int out_size, void* d_ws, size_t ws_size,
                              hipStream_t stream) {
    const float* positions = (const float*)d_in[0];
    const float* features  = (const float*)d_in[1];
    const int*   faces     = (const int*)  d_in[2];
    const float* K         = (const float*)d_in[3];
    const float* RT        = (const float*)d_in[4];
    int Fn = in_sizes[2] / 3;   // 16384

    // Workspace: keys cleared by k_pre; one small 0x00 memset covers
    // hist | histcur | gbb(4, all-atomicMax encoding).
    ull*      keys     = (ull*)d_ws;                    // H*W * 8 B
    unsigned* hist     = (unsigned*)(keys + H_*W_);     // 256 words
    unsigned* histcur  = hist + NBUCKET;                // 256 words
    unsigned* gbb      = histcur + NBUCKET;             // 4 words
    float*    suffz    = (float*)(gbb + 4);             // 64 floats (scatter blk0)
    float*    rec      = suffz + MAXCHUNK;              // Fn*20 floats (depth-sorted)
    float*    rec0     = rec + (size_t)Fn*20;           // Fn*12 floats (unsorted)

    size_t regB = (NBUCKET*2 + 4)*4;
    hipMemsetAsync(hist, 0x00, regB, stream);

    int nfb = (Fn + 255) / 256;
    k_pre<<<(Fn+63)/64, 64, 0, stream>>>(positions, K, RT, faces, rec0, hist, gbb, keys, Fn);
    k_scatter<<<nfb, 256, 0, stream>>>(rec0, hist, histcur, rec, suffz, Fn);
    dim3 rg(NTX, NTY, NSLICE);
    k_raster<<<rg, dim3(256,1,1), 0, stream>>>(rec, suffz, gbb, keys, Fn);
    k_post<<<(H_*W_)/4, 256, 0, stream>>>(keys, rec0, features, faces, (float*)d_out);
}